// Round 8
// baseline (153.556 us; speedup 1.0000x reference)
//
#include <hip/hip_runtime.h>

#define EMB 256
#define HD 32
#define SEQ 4096
#define NSPLIT 8      // key splits = waves per attn block (merged in LDS)
#define KRANGE 512    // keys per wave
#define NT (KRANGE / 32)
#define NQROW 16384   // B*S

typedef _Float16 half8 __attribute__((ext_vector_type(8)));
typedef _Float16 half4v __attribute__((ext_vector_type(4)));
typedef _Float16 half2v __attribute__((ext_vector_type(2)));
typedef float floatx4 __attribute__((ext_vector_type(4)));
typedef float floatx16 __attribute__((ext_vector_type(16)));
typedef unsigned uint2v __attribute__((ext_vector_type(2)));

#define L2E 1.44269504088896340736f
#define SCALING 0.17677669529663687f   // 32^-0.5, applied POST-softmax
#define DEFER_THR 8.0f                 // exp2-domain defer-max threshold: p <= 2^8

__device__ __forceinline__ half8 mk8(unsigned a, unsigned b, unsigned c, unsigned d) {
  union { unsigned u[4]; half8 h; } z;
  z.u[0] = a; z.u[1] = b; z.u[2] = c; z.u[3] = d;
  return z.h;
}

// permlane32_swap semantics: a' = {a.lo, b.lo}, b' = {a.hi, b.hi}
__device__ __forceinline__ void plswap(unsigned& a, unsigned& b) {
#if __has_builtin(__builtin_amdgcn_permlane32_swap)
  uint2v r = __builtin_amdgcn_permlane32_swap(a, b, false, false);
  a = r[0]; b = r[1];
#else
  unsigned sa = (unsigned)__shfl_xor((int)a, 32);
  unsigned sb = (unsigned)__shfl_xor((int)b, 32);
  bool hi = (threadIdx.x & 32) != 0;
  unsigned na = hi ? sb : a;
  unsigned nb = hi ? b : sa;
  a = na; b = nb;
#endif
}

// sum of the two f16 halves of pk into acc (consistent with the f16 P fed to PV MFMA)
__device__ __forceinline__ float sum2(unsigned pk, float acc) {
  half2v a = __builtin_bit_cast(half2v, pk);
#if __has_builtin(__builtin_amdgcn_fdot2)
  half2v one; one[0] = (_Float16)1.f; one[1] = (_Float16)1.f;
  return __builtin_amdgcn_fdot2(a, one, acc, false);
#else
  return acc + (float)a[0] + (float)a[1];
#endif
}

// ---------------- Kernel 1: QKV projection, task = (rowgroup64, matrix) --------------------
// 768 blocks x 256 thr = 3 blocks/CU, 12 waves/CU (was 1 block/CU => no latency hiding).
// Each block swizzles ONE matrix (32 KB f32 -> 16 KB f16 LDS, B-frag order), then the
// round-0-verified one-mat wave body: 4 waves x 16 rows, 2 MFMA per kc.
__global__ __launch_bounds__(256) void qkv_kernel(const float* __restrict__ x,
                                                  const float* __restrict__ Wq,
                                                  const float* __restrict__ Wk,
                                                  const float* __restrict__ Wv,
                                                  _Float16* __restrict__ qw,
                                                  _Float16* __restrict__ kw,
                                                  _Float16* __restrict__ vt2) {
  __shared__ _Float16 wsl[8192];    // 16 KB: [half][kc][lane][j] f16, one matrix
  const int tid = threadIdx.x;
  const int mat = blockIdx.x >> 8;           // 0..2  (256 rowgroup-blocks per matrix)
  const int rg  = blockIdx.x & 255;

  const float* W = (mat == 0) ? Wq : ((mat == 1) ? Wk : Wv);
  const float sc = (mat == 0) ? L2E : 1.f;   // Wq pre-scaled: exp2-domain scores for free

  // Coalesced one-mat W load + swizzle into LDS (B-frag order).
#pragma unroll
  for (int i = 0; i < 8; ++i) {
    int lu = i * 1024 + tid * 4;             // flat f32 idx within the matrix
    float4 v4 = *(const float4*)(W + lu);
    int e = lu >> 5;                          // emb row
    int d0 = lu & 31;                         // head-dim base (mult of 4, same half)
    int kc = e >> 5, quad = (e >> 3) & 3, j = e & 7;
    int half = d0 >> 4;
    int n0 = d0 & 15;
    int base = ((half * 8 + kc) << 9) + (quad << 7) + j;
    wsl[base + (n0 + 0) * 8] = (_Float16)(v4.x * sc);
    wsl[base + (n0 + 1) * 8] = (_Float16)(v4.y * sc);
    wsl[base + (n0 + 2) * 8] = (_Float16)(v4.z * sc);
    wsl[base + (n0 + 3) * 8] = (_Float16)(v4.w * sc);
  }
  __syncthreads();

  int lane = tid & 63, wave = tid >> 6;
  int n = lane & 15, quad = lane >> 4;
  int rowbase = rg * 64 + wave * 16;

  floatx4 c0 = {0,0,0,0}, c1 = {0,0,0,0};

#pragma unroll
  for (int kc = 0; kc < 8; ++kc) {
    const float* xp = x + (size_t)(rowbase + n) * EMB + kc * 32 + quad * 8;
    float4 xa = *(const float4*)(xp);
    float4 xb = *(const float4*)(xp + 4);
    half8 a;
    a[0] = (_Float16)xa.x; a[1] = (_Float16)xa.y; a[2] = (_Float16)xa.z; a[3] = (_Float16)xa.w;
    a[4] = (_Float16)xb.x; a[5] = (_Float16)xb.y; a[6] = (_Float16)xb.z; a[7] = (_Float16)xb.w;
    half8 b0 = *(const half8*)(wsl + (kc << 9) + (lane << 3));
    half8 b1 = *(const half8*)(wsl + ((8 + kc) << 9) + (lane << 3));
    c0 = __builtin_amdgcn_mfma_f32_16x16x32_f16(a, b0, c0, 0, 0, 0);
    c1 = __builtin_amdgcn_mfma_f32_16x16x32_f16(a, b1, c1, 0, 0, 0);
  }

  if (mat == 2) {
    int b = rowbase >> 12;
    int s0 = rowbase & (SEQ - 1);
    _Float16* vb = vt2 + (size_t)b * SEQ * HD;
#pragma unroll
    for (int r = 0; r < 4; ++r) {
      int s = s0 + quad * 4 + r;
      int blk = (s >> 3) << 8, sl = s & 7;   // key-block base (8 keys x 32 d), slot
      vb[blk + n * 8 + sl]        = (_Float16)c0[r];
      vb[blk + (n + 16) * 8 + sl] = (_Float16)c1[r];
    }
  } else {
    _Float16* dst = (mat == 0) ? qw : kw;
#pragma unroll
    for (int r = 0; r < 4; ++r) {
      int row = rowbase + quad * 4 + r;
      dst[row * HD + n]      = (_Float16)c0[r];
      dst[row * HD + n + 16] = (_Float16)c1[r];
    }
  }
}

// ---------------- Kernel 2: flash attention + in-block LDS split-K merge -------------------
// 512 blocks x 512 thr (8 waves). launch_bounds(512, 8) forces <=64 VGPR (R6 measured
// exactly 64 for this loop) => 4 blocks/CU, 32 waves/CU (LDS 38.2 KB x 4 = 153 <= 160 KB).
// Wave w handles key-split sp=w (512 keys, 16 tiles); merge via __syncthreads + LDS.
__global__ __launch_bounds__(512, 8) void attn_kernel(const _Float16* __restrict__ q,
                                                      const _Float16* __restrict__ k,
                                                      const _Float16* __restrict__ vt2,
                                                      float* __restrict__ out) {
  // sO stride 36 words: pads row to break the d-column bank alignment.
  __shared__ float sO[NSPLIT * 32 * 36];   // 36 KB
  __shared__ float sM[NSPLIT * 32];
  __shared__ float sL[NSPLIT * 32];

  const int t = threadIdx.x;
  const int w = t >> 6, lane = t & 63;     // w = wave = key-split
  const int n2 = lane & 31, h = lane >> 5;
  const int qrow0 = blockIdx.x * 32;
  const int b = qrow0 >> 12;
  const int key0 = w * KRANGE;

  const _Float16* kb = k   + (size_t)(b * SEQ + key0) * HD;
  const _Float16* vb = vt2 + (size_t)b * SEQ * HD + (size_t)key0 * HD;

  // Q^T B-frags (pre-scaled by L2E): B[k=d][n=qrow=n2]
  half8 qf0 = *(const half8*)(q + (qrow0 + n2) * HD + h * 8);
  half8 qf1 = *(const half8*)(q + (qrow0 + n2) * HD + 16 + h * 8);

  floatx16 o;
#pragma unroll
  for (int r = 0; r < 16; ++r) o[r] = 0.f;
  const floatx16 zero16 = o;
  float m = -__builtin_huge_valf();      // deferred reference max (exp2 domain)
  float mtrue = -__builtin_huge_valf();  // true running max (for epilogue rescale)
  float l = 0.f;

  auto ldt = [&](int tile, half8& k0, half8& k1, half8& v0, half8& v1) {
    const _Float16* kn = kb + (size_t)(tile * 32 + n2) * HD;
    const _Float16* vn = vb + tile * 1024;
    k0 = *(const half8*)(kn + h * 8);
    k1 = *(const half8*)(kn + 16 + h * 8);
    v0 = *(const half8*)(vn + h * 256 + n2 * 8);
    v1 = *(const half8*)(vn + 512 + h * 256 + n2 * 8);
  };

  auto tilecomp = [&](half8 tka0, half8 tka1, half8 tva0, half8 tva1) {
    // S^T tile [32 keys x 32 qrows]
    floatx16 s = __builtin_amdgcn_mfma_f32_32x32x16_f16(tka0, qf0, zero16, 0, 0, 0);
    s = __builtin_amdgcn_mfma_f32_32x32x16_f16(tka1, qf1, s, 0, 0, 0);

    floatx4 s0 = {s[0], s[1], s[2], s[3]};
    floatx4 s1 = {s[4], s[5], s[6], s[7]};
    floatx4 s2 = {s[8], s[9], s[10], s[11]};
    floatx4 s3 = {s[12], s[13], s[14], s[15]};
    floatx4 t01 = __builtin_elementwise_max(s0, s1);
    floatx4 t23 = __builtin_elementwise_max(s2, s3);
    floatx4 t4  = __builtin_elementwise_max(t01, t23);
    float mm = fmaxf(fmaxf(t4[0], t4[1]), fmaxf(t4[2], t4[3]));
    mm = fmaxf(mm, __shfl_xor(mm, 32));
    mtrue = fmaxf(mtrue, mm);

    // defer-max: only rescale when some row's max grew past THR (wave-uniform branch)
    if (__any(mm > m + DEFER_THR)) {
      float mnew = fmaxf(m, mm);
      float alpha = __builtin_amdgcn_exp2f(m - mnew);
      m = mnew;
#pragma unroll
      for (int r = 0; r < 16; ++r) o[r] *= alpha;
      l *= alpha;
    }

    // p = exp2(s - m) <= 2^THR, pack consecutive-key pairs
    unsigned pk[8];
#pragma unroll
    for (int g = 0; g < 8; ++g) {
      float p0 = __builtin_amdgcn_exp2f(s[2 * g] - m);
      float p1 = __builtin_amdgcn_exp2f(s[2 * g + 1] - m);
      pk[g] = __builtin_bit_cast(unsigned, __builtin_amdgcn_cvt_pkrtz(p0, p1));
    }

    // l partial: own 16 keys via f16 dot2 (partner merged once after the loop)
    float lA = sum2(pk[3], sum2(pk[2], sum2(pk[1], sum2(pk[0], 0.f))));
    float lB = sum2(pk[7], sum2(pk[6], sum2(pk[5], sum2(pk[4], 0.f))));
    l += lA + lB;

    // P^T B-frags via permlane32_swap
    unsigned b00 = pk[0], b02 = pk[2]; plswap(b00, b02);
    unsigned b01 = pk[1], b03 = pk[3]; plswap(b01, b03);
    unsigned b10 = pk[4], b12 = pk[6]; plswap(b10, b12);
    unsigned b11 = pk[5], b13 = pk[7]; plswap(b11, b13);

    // O^T += V^T · P^T  (two key halves)
    o = __builtin_amdgcn_mfma_f32_32x32x16_f16(tva0, mk8(b00, b01, b02, b03), o, 0, 0, 0);
    o = __builtin_amdgcn_mfma_f32_32x32x16_f16(tva1, mk8(b10, b11, b12, b13), o, 0, 0, 0);
  };

  // depth-2 pipeline: preload tiles 0 and 1; in body kt, issue kt+2 / kt+3.
  half8 ak0, ak1, av0, av1, bk0, bk1, bv0, bv1;
  ldt(0, ak0, ak1, av0, av1);
  ldt(1, bk0, bk1, bv0, bv1);

#pragma unroll
  for (int kt = 0; kt < NT; kt += 2) {
    half8 ck0, ck1, cv0, cv1, dk0, dk1, dv0, dv1;
    ldt((kt + 2) & (NT - 1), ck0, ck1, cv0, cv1);   // wrap: harmless reload on tail
    tilecomp(ak0, ak1, av0, av1);
    ldt((kt + 3) & (NT - 1), dk0, dk1, dv0, dv1);
    tilecomp(bk0, bk1, bv0, bv1);
    ak0 = ck0; ak1 = ck1; av0 = cv0; av1 = cv1;
    bk0 = dk0; bk1 = dk1; bv0 = dv0; bv1 = dv1;
  }

  // epilogue: rescale to the true max (p_eff <= 1), publish split result to LDS
  float scale = __builtin_amdgcn_exp2f(m - mtrue);
  l *= scale;
  l = l + __shfl_xor(l, 32);

  // lane(n2,h) reg r -> qrow=n2, d=(r&3)+8*(r>>2)+4h; b128 stores into padded rows
#pragma unroll
  for (int bb = 0; bb < 4; ++bb) {
    floatx4 pv = {o[4 * bb + 0] * scale, o[4 * bb + 1] * scale,
                  o[4 * bb + 2] * scale, o[4 * bb + 3] * scale};
    *(floatx4*)&sO[w * 1152 + n2 * 36 + 8 * bb + 4 * h] = pv;
  }
  if (h == 0) {
    sM[w * 32 + n2] = mtrue;
    sL[w * 32 + n2] = l;
  }
  __syncthreads();

  // in-block merge of the 8 splits: 32 rows x 32 d = 1024 outputs, 512 threads x 2
#pragma unroll
  for (int it = 0; it < 2; ++it) {
    int idx = it * 512 + t;
    int qr = idx >> 5, d = idx & 31;
    float mv[NSPLIT];
    float ms = -__builtin_huge_valf();
#pragma unroll
    for (int w2 = 0; w2 < NSPLIT; ++w2) {
      mv[w2] = sM[w2 * 32 + qr];
      ms = fmaxf(ms, mv[w2]);
    }
    float L = 0.f, O = 0.f;
#pragma unroll
    for (int w2 = 0; w2 < NSPLIT; ++w2) {
      float ww = __builtin_amdgcn_exp2f(mv[w2] - ms);
      L += ww * sL[w2 * 32 + qr];
      O += ww * sO[w2 * 1152 + qr * 36 + d];
    }
    out[(size_t)(qrow0 + qr) * HD + d] = O * SCALING / L;
  }
}

extern "C" void kernel_launch(void* const* d_in, const int* in_sizes, int n_in,
                              void* d_out, int out_size, void* d_ws, size_t ws_size,
                              hipStream_t stream) {
  const float* x  = (const float*)d_in[0];
  const float* Wq = (const float*)d_in[1];
  const float* Wk = (const float*)d_in[2];
  const float* Wv = (const float*)d_in[3];
  float* out = (float*)d_out;

  _Float16* qw  = (_Float16*)d_ws;          // [16384][32]
  _Float16* kw  = qw + NQROW * HD;          // [16384][32]
  _Float16* vt2 = kw + NQROW * HD;          // [4][512][32][8] key-tiled V

  qkv_kernel<<<768, 256, 0, stream>>>(x, Wq, Wk, Wv, qw, kw, vt2);
  attn_kernel<<<512, 512, 0, stream>>>(qw, kw, vt2, out);
}

// Round 10
// 93.638 us; speedup vs baseline: 1.6399x; 1.6399x over previous
//
#include <hip/hip_runtime.h>

#define EMB 256
#define HD 32
#define SEQ 4096
#define NSPLIT 8      // key splits = waves per attn block (merged in LDS)
#define KRANGE 512    // keys per wave
#define NT (KRANGE / 32)
#define NQROW 16384   // B*S

typedef _Float16 half8 __attribute__((ext_vector_type(8)));
typedef _Float16 half4v __attribute__((ext_vector_type(4)));
typedef _Float16 half2v __attribute__((ext_vector_type(2)));
typedef float floatx4 __attribute__((ext_vector_type(4)));
typedef float floatx16 __attribute__((ext_vector_type(16)));
typedef unsigned uint2v __attribute__((ext_vector_type(2)));

#define L2E 1.44269504088896340736f
#define SCALING 0.17677669529663687f   // 32^-0.5, applied POST-softmax
#define DEFER_THR 8.0f                 // exp2-domain defer-max threshold: p <= 2^8

__device__ __forceinline__ half8 mk8(unsigned a, unsigned b, unsigned c, unsigned d) {
  union { unsigned u[4]; half8 h; } z;
  z.u[0] = a; z.u[1] = b; z.u[2] = c; z.u[3] = d;
  return z.h;
}

// permlane32_swap semantics: a' = {a.lo, b.lo}, b' = {a.hi, b.hi}
__device__ __forceinline__ void plswap(unsigned& a, unsigned& b) {
#if __has_builtin(__builtin_amdgcn_permlane32_swap)
  uint2v r = __builtin_amdgcn_permlane32_swap(a, b, false, false);
  a = r[0]; b = r[1];
#else
  unsigned sa = (unsigned)__shfl_xor((int)a, 32);
  unsigned sb = (unsigned)__shfl_xor((int)b, 32);
  bool hi = (threadIdx.x & 32) != 0;
  unsigned na = hi ? sb : a;
  unsigned nb = hi ? b : sa;
  a = na; b = nb;
#endif
}

// sum of the two f16 halves of pk into acc (consistent with the f16 P fed to PV MFMA)
__device__ __forceinline__ float sum2(unsigned pk, float acc) {
  half2v a = __builtin_bit_cast(half2v, pk);
#if __has_builtin(__builtin_amdgcn_fdot2)
  half2v one; one[0] = (_Float16)1.f; one[1] = (_Float16)1.f;
  return __builtin_amdgcn_fdot2(a, one, acc, false);
#else
  return acc + (float)a[0] + (float)a[1];
#endif
}

// ---------------- Kernel 1: QKV projection, task = (rowgroup64, matrix) --------------------
// 768 blocks x 256 thr = 3 blocks/CU, 12 waves/CU. Each block swizzles ONE matrix
// (32 KB f32 -> 16 KB f16 LDS, B-frag order), then the verified one-mat wave body.
__global__ __launch_bounds__(256) void qkv_kernel(const float* __restrict__ x,
                                                  const float* __restrict__ Wq,
                                                  const float* __restrict__ Wk,
                                                  const float* __restrict__ Wv,
                                                  _Float16* __restrict__ qw,
                                                  _Float16* __restrict__ kw,
                                                  _Float16* __restrict__ vt2) {
  __shared__ _Float16 wsl[8192];    // 16 KB: [half][kc][lane][j] f16, one matrix
  const int tid = threadIdx.x;
  const int mat = blockIdx.x >> 8;           // 0..2  (256 rowgroup-blocks per matrix)
  const int rg  = blockIdx.x & 255;

  const float* W = (mat == 0) ? Wq : ((mat == 1) ? Wk : Wv);
  const float sc = (mat == 0) ? L2E : 1.f;   // Wq pre-scaled: exp2-domain scores for free

  // Coalesced one-mat W load + swizzle into LDS (B-frag order).
#pragma unroll
  for (int i = 0; i < 8; ++i) {
    int lu = i * 1024 + tid * 4;             // flat f32 idx within the matrix
    float4 v4 = *(const float4*)(W + lu);
    int e = lu >> 5;                          // emb row
    int d0 = lu & 31;                         // head-dim base (mult of 4, same half)
    int kc = e >> 5, quad = (e >> 3) & 3, j = e & 7;
    int half = d0 >> 4;
    int n0 = d0 & 15;
    int base = ((half * 8 + kc) << 9) + (quad << 7) + j;
    wsl[base + (n0 + 0) * 8] = (_Float16)(v4.x * sc);
    wsl[base + (n0 + 1) * 8] = (_Float16)(v4.y * sc);
    wsl[base + (n0 + 2) * 8] = (_Float16)(v4.z * sc);
    wsl[base + (n0 + 3) * 8] = (_Float16)(v4.w * sc);
  }
  __syncthreads();

  int lane = tid & 63, wave = tid >> 6;
  int n = lane & 15, quad = lane >> 4;
  int rowbase = rg * 64 + wave * 16;

  floatx4 c0 = {0,0,0,0}, c1 = {0,0,0,0};

#pragma unroll
  for (int kc = 0; kc < 8; ++kc) {
    const float* xp = x + (size_t)(rowbase + n) * EMB + kc * 32 + quad * 8;
    float4 xa = *(const float4*)(xp);
    float4 xb = *(const float4*)(xp + 4);
    half8 a;
    a[0] = (_Float16)xa.x; a[1] = (_Float16)xa.y; a[2] = (_Float16)xa.z; a[3] = (_Float16)xa.w;
    a[4] = (_Float16)xb.x; a[5] = (_Float16)xb.y; a[6] = (_Float16)xb.z; a[7] = (_Float16)xb.w;
    half8 b0 = *(const half8*)(wsl + (kc << 9) + (lane << 3));
    half8 b1 = *(const half8*)(wsl + ((8 + kc) << 9) + (lane << 3));
    c0 = __builtin_amdgcn_mfma_f32_16x16x32_f16(a, b0, c0, 0, 0, 0);
    c1 = __builtin_amdgcn_mfma_f32_16x16x32_f16(a, b1, c1, 0, 0, 0);
  }

  if (mat == 2) {
    int b = rowbase >> 12;
    int s0 = rowbase & (SEQ - 1);
    _Float16* vb = vt2 + (size_t)b * SEQ * HD;
#pragma unroll
    for (int r = 0; r < 4; ++r) {
      int s = s0 + quad * 4 + r;
      int blk = (s >> 3) << 8, sl = s & 7;   // key-block base (8 keys x 32 d), slot
      vb[blk + n * 8 + sl]        = (_Float16)c0[r];
      vb[blk + (n + 16) * 8 + sl] = (_Float16)c1[r];
    }
  } else {
    _Float16* dst = (mat == 0) ? qw : kw;
#pragma unroll
    for (int r = 0; r < 4; ++r) {
      int row = rowbase + quad * 4 + r;
      dst[row * HD + n]      = (_Float16)c0[r];
      dst[row * HD + n + 16] = (_Float16)c1[r];
    }
  }
}

// ---------------- Kernel 2: flash attention + in-block LDS split-K merge -------------------
// ROUND-7 VERIFIED VERSION, byte-identical: launch_bounds(512, 4). R8's (512,8) capped the
// allocator at 32 VGPR -> 330 MB scratch spill per dispatch (FETCH 141 MB / WRITE 191 MB).
__global__ __launch_bounds__(512, 4) void attn_kernel(const _Float16* __restrict__ q,
                                                      const _Float16* __restrict__ k,
                                                      const _Float16* __restrict__ vt2,
                                                      float* __restrict__ out) {
  // sO stride 36 words: pads row to break the d-column bank alignment.
  __shared__ float sO[NSPLIT * 32 * 36];   // 36 KB
  __shared__ float sM[NSPLIT * 32];
  __shared__ float sL[NSPLIT * 32];

  const int t = threadIdx.x;
  const int w = t >> 6, lane = t & 63;     // w = wave = key-split
  const int n2 = lane & 31, h = lane >> 5;
  const int qrow0 = blockIdx.x * 32;
  const int b = qrow0 >> 12;
  const int key0 = w * KRANGE;

  const _Float16* kb = k   + (size_t)(b * SEQ + key0) * HD;
  const _Float16* vb = vt2 + (size_t)b * SEQ * HD + (size_t)key0 * HD;

  // Q^T B-frags (pre-scaled by L2E): B[k=d][n=qrow=n2]
  half8 qf0 = *(const half8*)(q + (qrow0 + n2) * HD + h * 8);
  half8 qf1 = *(const half8*)(q + (qrow0 + n2) * HD + 16 + h * 8);

  floatx16 o;
#pragma unroll
  for (int r = 0; r < 16; ++r) o[r] = 0.f;
  const floatx16 zero16 = o;
  float m = -__builtin_huge_valf();      // deferred reference max (exp2 domain)
  float mtrue = -__builtin_huge_valf();  // true running max (for epilogue rescale)
  float l = 0.f;

  auto ldt = [&](int tile, half8& k0, half8& k1, half8& v0, half8& v1) {
    const _Float16* kn = kb + (size_t)(tile * 32 + n2) * HD;
    const _Float16* vn = vb + tile * 1024;
    k0 = *(const half8*)(kn + h * 8);
    k1 = *(const half8*)(kn + 16 + h * 8);
    v0 = *(const half8*)(vn + h * 256 + n2 * 8);
    v1 = *(const half8*)(vn + 512 + h * 256 + n2 * 8);
  };

  auto tilecomp = [&](half8 tka0, half8 tka1, half8 tva0, half8 tva1) {
    // S^T tile [32 keys x 32 qrows]
    floatx16 s = __builtin_amdgcn_mfma_f32_32x32x16_f16(tka0, qf0, zero16, 0, 0, 0);
    s = __builtin_amdgcn_mfma_f32_32x32x16_f16(tka1, qf1, s, 0, 0, 0);

    floatx4 s0 = {s[0], s[1], s[2], s[3]};
    floatx4 s1 = {s[4], s[5], s[6], s[7]};
    floatx4 s2 = {s[8], s[9], s[10], s[11]};
    floatx4 s3 = {s[12], s[13], s[14], s[15]};
    floatx4 t01 = __builtin_elementwise_max(s0, s1);
    floatx4 t23 = __builtin_elementwise_max(s2, s3);
    floatx4 t4  = __builtin_elementwise_max(t01, t23);
    float mm = fmaxf(fmaxf(t4[0], t4[1]), fmaxf(t4[2], t4[3]));
    mm = fmaxf(mm, __shfl_xor(mm, 32));
    mtrue = fmaxf(mtrue, mm);

    // defer-max: only rescale when some row's max grew past THR (wave-uniform branch)
    if (__any(mm > m + DEFER_THR)) {
      float mnew = fmaxf(m, mm);
      float alpha = __builtin_amdgcn_exp2f(m - mnew);
      m = mnew;
#pragma unroll
      for (int r = 0; r < 16; ++r) o[r] *= alpha;
      l *= alpha;
    }

    // p = exp2(s - m) <= 2^THR, pack consecutive-key pairs
    unsigned pk[8];
#pragma unroll
    for (int g = 0; g < 8; ++g) {
      float p0 = __builtin_amdgcn_exp2f(s[2 * g] - m);
      float p1 = __builtin_amdgcn_exp2f(s[2 * g + 1] - m);
      pk[g] = __builtin_bit_cast(unsigned, __builtin_amdgcn_cvt_pkrtz(p0, p1));
    }

    // l partial: own 16 keys via f16 dot2 (partner merged once after the loop)
    float lA = sum2(pk[3], sum2(pk[2], sum2(pk[1], sum2(pk[0], 0.f))));
    float lB = sum2(pk[7], sum2(pk[6], sum2(pk[5], sum2(pk[4], 0.f))));
    l += lA + lB;

    // P^T B-frags via permlane32_swap
    unsigned b00 = pk[0], b02 = pk[2]; plswap(b00, b02);
    unsigned b01 = pk[1], b03 = pk[3]; plswap(b01, b03);
    unsigned b10 = pk[4], b12 = pk[6]; plswap(b10, b12);
    unsigned b11 = pk[5], b13 = pk[7]; plswap(b11, b13);

    // O^T += V^T · P^T  (two key halves)
    o = __builtin_amdgcn_mfma_f32_32x32x16_f16(tva0, mk8(b00, b01, b02, b03), o, 0, 0, 0);
    o = __builtin_amdgcn_mfma_f32_32x32x16_f16(tva1, mk8(b10, b11, b12, b13), o, 0, 0, 0);
  };

  // depth-2 pipeline: preload tiles 0 and 1; in body kt, issue kt+2 / kt+3.
  half8 ak0, ak1, av0, av1, bk0, bk1, bv0, bv1;
  ldt(0, ak0, ak1, av0, av1);
  ldt(1, bk0, bk1, bv0, bv1);

#pragma unroll
  for (int kt = 0; kt < NT; kt += 2) {
    half8 ck0, ck1, cv0, cv1, dk0, dk1, dv0, dv1;
    ldt((kt + 2) & (NT - 1), ck0, ck1, cv0, cv1);   // wrap: harmless reload on tail
    tilecomp(ak0, ak1, av0, av1);
    ldt((kt + 3) & (NT - 1), dk0, dk1, dv0, dv1);
    tilecomp(bk0, bk1, bv0, bv1);
    ak0 = ck0; ak1 = ck1; av0 = cv0; av1 = cv1;
    bk0 = dk0; bk1 = dk1; bv0 = dv0; bv1 = dv1;
  }

  // epilogue: rescale to the true max (p_eff <= 1), publish split result to LDS
  float scale = __builtin_amdgcn_exp2f(m - mtrue);
  l *= scale;
  l = l + __shfl_xor(l, 32);

  // lane(n2,h) reg r -> qrow=n2, d=(r&3)+8*(r>>2)+4h; b128 stores into padded rows
#pragma unroll
  for (int bb = 0; bb < 4; ++bb) {
    floatx4 pv = {o[4 * bb + 0] * scale, o[4 * bb + 1] * scale,
                  o[4 * bb + 2] * scale, o[4 * bb + 3] * scale};
    *(floatx4*)&sO[w * 1152 + n2 * 36 + 8 * bb + 4 * h] = pv;
  }
  if (h == 0) {
    sM[w * 32 + n2] = mtrue;
    sL[w * 32 + n2] = l;
  }
  __syncthreads();

  // in-block merge of the 8 splits: 32 rows x 32 d = 1024 outputs, 512 threads x 2
#pragma unroll
  for (int it = 0; it < 2; ++it) {
    int idx = it * 512 + t;
    int qr = idx >> 5, d = idx & 31;
    float mv[NSPLIT];
    float ms = -__builtin_huge_valf();
#pragma unroll
    for (int w2 = 0; w2 < NSPLIT; ++w2) {
      mv[w2] = sM[w2 * 32 + qr];
      ms = fmaxf(ms, mv[w2]);
    }
    float L = 0.f, O = 0.f;
#pragma unroll
    for (int w2 = 0; w2 < NSPLIT; ++w2) {
      float ww = __builtin_amdgcn_exp2f(mv[w2] - ms);
      L += ww * sL[w2 * 32 + qr];
      O += ww * sO[w2 * 1152 + qr * 36 + d];
    }
    out[(size_t)(qrow0 + qr) * HD + d] = O * SCALING / L;
  }
}

extern "C" void kernel_launch(void* const* d_in, const int* in_sizes, int n_in,
                              void* d_out, int out_size, void* d_ws, size_t ws_size,
                              hipStream_t stream) {
  const float* x  = (const float*)d_in[0];
  const float* Wq = (const float*)d_in[1];
  const float* Wk = (const float*)d_in[2];
  const float* Wv = (const float*)d_in[3];
  float* out = (float*)d_out;

  _Float16* qw  = (_Float16*)d_ws;          // [16384][32]
  _Float16* kw  = qw + NQROW * HD;          // [16384][32]
  _Float16* vt2 = kw + NQROW * HD;          // [4][512][32][8] key-tiled V

  qkv_kernel<<<768, 256, 0, stream>>>(x, Wq, Wk, Wv, qw, kw, vt2);
  attn_kernel<<<512, 512, 0, stream>>>(qw, kw, vt2, out);
}